// Round 11
// baseline (513.923 us; speedup 1.0000x reference)
//
#include <hip/hip_runtime.h>
#include <hip/hip_bf16.h>
#include <stdint.h>

#define HEIGHT 32
#define WIDTH  8192
#define KDIM   256
#define NDIM   512
#define NSLICES 65536                       // B * S = 64 * 1024
#define NMTILES 2048                        // BM = 32
#define WT_BYTES (NDIM * KDIM * 2)          // 256 KB
#define FEATS_BYTES ((size_t)NSLICES * KDIM * 2)  // 33.5 MB
#define FLAGS_BYTES (NMTILES * 4)
#define MAGIC 0x1234ABCDu
#define POLLS 300

typedef float f32x4  __attribute__((ext_vector_type(4)));
typedef float f32x16 __attribute__((ext_vector_type(16)));
typedef short bf16x8 __attribute__((ext_vector_type(8)));

__device__ __forceinline__ ushort f2bf(float x) {
  union { float f; uint32_t u; } un; un.f = x;
  uint32_t u = un.u;
  u += 0x7FFFu + ((u >> 16) & 1u);   // round-to-nearest-even
  return (ushort)(u >> 16);
}

__device__ __forceinline__ void load_row8(float* r, const float* p) {
  f32x4 lo = *reinterpret_cast<const f32x4*>(p);
  f32x4 hi = *reinterpret_cast<const f32x4*>(p + 4);
#pragma unroll
  for (int w = 0; w < 4; ++w) { r[w] = lo[w]; r[4 + w] = hi[w]; }
}

// ---- wt2: B-fragment-tiled layout (proven R7/R8) ----
__global__ __launch_bounds__(256) void prep_wt2_kernel(const float* __restrict__ lin_w,
                                                       ushort* __restrict__ wt2) {
  const int idx = blockIdx.x * 256 + threadIdx.x;   // 0..16383
  const int ln  = idx & 63;
  const int k0  = (idx >> 6) & 15;
  const int nb  = idx >> 10;
  const int n   = nb * 32 + (ln & 31);
  const int kb  = k0 * 16 + (ln >> 5) * 8;
  bf16x8 p;
#pragma unroll
  for (int e = 0; e < 8; ++e) p[e] = (short)f2bf(lin_w[(size_t)(kb + e) * NDIM + n]);
  *reinterpret_cast<bf16x8*>(wt2 + (size_t)idx * 8) = p;
}

// conv one mtile (32 slices x 32 rows) into A-fragment order at dst:
// dst[((k0)*64 + ln)*8 + e], ln = ((h&1)<<5)|sl, k0 = h>>1.
__device__ __forceinline__ void conv_tile_to(const float* __restrict__ images,
                                             const float* cw, float cb,
                                             int mtile, int tid, ushort* dst) {
  const int sl = tid & 31;
  const int q  = tid >> 5;            // 0..7, rows q*4..q*4+3
  const int s  = mtile * 32 + sl;
  const int b  = s >> 10;
  const int slb = s & 1023;
  const float* base = images + (size_t)b * (HEIGHT * WIDTH) + (size_t)slb * 8;
  const int h0 = q * 4;

  float r[6][8];
#pragma unroll
  for (int i = 0; i < 6; ++i) {
    const int h = h0 - 1 + i;
    if (h >= 0 && h < HEIGHT) load_row8(r[i], base + (size_t)h * WIDTH);
    else {
#pragma unroll
      for (int w = 0; w < 8; ++w) r[i][w] = 0.f;
    }
  }

#pragma unroll
  for (int oh = 0; oh < 4; ++oh) {
    const int h = h0 + oh;
    float y[8];
#pragma unroll
    for (int w = 0; w < 8; ++w) y[w] = cb;
#pragma unroll
    for (int dh = 0; dh < 3; ++dh) {
#pragma unroll
      for (int dw = 0; dw < 3; ++dw) {
        const float c = cw[dh * 3 + dw];
#pragma unroll
        for (int w = 0; w < 8; ++w) {
          const int iw = w + dw - 1;          // per-slice zero padding in w
          if (iw >= 0 && iw < 8) y[w] = fmaf(r[oh + dh][iw], c, y[w]);
        }
      }
    }
    bf16x8 pack;
#pragma unroll
    for (int w = 0; w < 8; ++w) pack[w] = (short)f2bf(fmaxf(y[w], 0.f));
    const int ln = ((h & 1) << 5) | sl;
    const int k0 = h >> 1;
    *reinterpret_cast<bf16x8*>(dst + ((size_t)k0 * 64 + ln) * 8) = pack;
  }
}

// ---------------- producer/consumer kernel ----------------
// Grid 4096: interleaved producers (conv mtile -> feats2 + flag) and consumers
// (gemm mtile). Consumer bounded-spins on flag; on timeout self-convs into LDS.
__global__ __launch_bounds__(256) void pc_kernel(
    const float* __restrict__ images, const float* __restrict__ conv_w,
    const float* __restrict__ conv_b, const ushort* __restrict__ wt2,
    const float* __restrict__ lin_b, float* __restrict__ out,
    ushort* __restrict__ feats2, unsigned int* __restrict__ flags) {
  __shared__ ushort A[16 * 64 * 8];   // 16 KB, consumer fallback only
  __shared__ int ready_s;

  const int idx = blockIdx.x;
  const int tid = threadIdx.x;

  // interleaved role mapping: [p0..p1023][c0,p1024,c1,p1025,...][c1024..c2047]
  int role, m;
  if (idx < 1024) { role = 0; m = idx; }
  else if (idx < 3072) {
    const int z = idx - 1024;
    if ((z & 1) == 0) { role = 1; m = z >> 1; }
    else              { role = 0; m = 1024 + (z >> 1); }
  } else { role = 1; m = 1024 + (idx - 3072); }

  float cw[9];
#pragma unroll
  for (int i = 0; i < 9; ++i) cw[i] = conv_w[i];
  const float cb = conv_b[0];

  if (role == 0) {
    // ---------------- producer: conv mtile m -> feats2 ----------------
    conv_tile_to(images, cw, cb, m, tid, feats2 + (size_t)m * 8192);
    __threadfence();
    __syncthreads();
    if (tid == 0)
      __hip_atomic_store(&flags[m], MAGIC, __ATOMIC_RELEASE, __HIP_MEMORY_SCOPE_AGENT);
    return;
  }

  // ---------------- consumer: gemm mtile m ----------------
  if (tid == 0) {
    int ok = 0;
    for (int it = 0; it < POLLS; ++it) {
      if (__hip_atomic_load(&flags[m], __ATOMIC_ACQUIRE, __HIP_MEMORY_SCOPE_AGENT) == MAGIC) {
        ok = 1; break;
      }
      __builtin_amdgcn_s_sleep(4);
    }
    ready_s = ok;
  }
  __syncthreads();
  const int ready = ready_s;

  if (!ready) {                        // bounded-spin timeout: do the conv ourselves
    conv_tile_to(images, cw, cb, m, tid, A);
    __syncthreads();
  }

  const int lane = tid & 63;
  const int wv   = tid >> 6;
  const int la   = lane & 31;
  const int lb   = lane >> 5;

  f32x16 acc[4];
#pragma unroll
  for (int nf = 0; nf < 4; ++nf)
#pragma unroll
    for (int i = 0; i < 16; ++i) acc[nf][i] = 0.f;

  const ushort* bb = wt2 + ((size_t)(wv * 4) * 16) * 512 + (size_t)lane * 8;

  if (ready) {
    const ushort* abase = feats2 + (size_t)m * 8192 + (size_t)lane * 8;
#pragma unroll
    for (int k0 = 0; k0 < 16; ++k0) {
      const bf16x8 af = *reinterpret_cast<const bf16x8*>(abase + (size_t)k0 * 512);
      bf16x8 bfr[4];
#pragma unroll
      for (int nf = 0; nf < 4; ++nf)
        bfr[nf] = *reinterpret_cast<const bf16x8*>(bb + (size_t)(nf * 16 + k0) * 512);
#pragma unroll
      for (int nf = 0; nf < 4; ++nf)
        acc[nf] = __builtin_amdgcn_mfma_f32_32x32x16_bf16(af, bfr[nf], acc[nf], 0, 0, 0);
    }
  } else {
    const ushort* abase = A + (size_t)lane * 8;
#pragma unroll
    for (int k0 = 0; k0 < 16; ++k0) {
      const bf16x8 af = *reinterpret_cast<const bf16x8*>(abase + (size_t)k0 * 512);
      bf16x8 bfr[4];
#pragma unroll
      for (int nf = 0; nf < 4; ++nf)
        bfr[nf] = *reinterpret_cast<const bf16x8*>(bb + (size_t)(nf * 16 + k0) * 512);
#pragma unroll
      for (int nf = 0; nf < 4; ++nf)
        acc[nf] = __builtin_amdgcn_mfma_f32_32x32x16_bf16(af, bfr[nf], acc[nf], 0, 0, 0);
    }
  }

  const size_t row0 = (size_t)m * 32;
#pragma unroll
  for (int nf = 0; nf < 4; ++nf) {
    const int col = wv * 128 + nf * 32 + la;
    const float bias = lin_b[col];
#pragma unroll
    for (int reg = 0; reg < 16; ++reg) {
      const int rr = (reg & 3) + 8 * (reg >> 2) + 4 * lb;
      out[(row0 + rr) * NDIM + col] = acc[nf][reg] + bias;
    }
  }
}

// ---------------- fallback (ws too small): R8 fused monolith ----------------
__global__ __launch_bounds__(256) void fused_kernel(
    const float* __restrict__ images, const float* __restrict__ conv_w,
    const float* __restrict__ conv_b, const ushort* __restrict__ wt2,
    const float* __restrict__ lin_b, float* __restrict__ out) {
  __shared__ ushort A[16 * 64 * 8];
  const int tid = threadIdx.x;
  const int blk = blockIdx.x;

  float cw[9];
#pragma unroll
  for (int i = 0; i < 9; ++i) cw[i] = conv_w[i];
  const float cb = conv_b[0];

  conv_tile_to(images, cw, cb, blk, tid, A);
  __syncthreads();

  const int lane = tid & 63;
  const int wv   = tid >> 6;
  const int la   = lane & 31;
  const int lb   = lane >> 5;

  const ushort* abase = A + (size_t)lane * 8;
  const ushort* bb = wt2 + ((size_t)(wv * 4) * 16) * 512 + (size_t)lane * 8;

  f32x16 acc[4];
#pragma unroll
  for (int nf = 0; nf < 4; ++nf)
#pragma unroll
    for (int i = 0; i < 16; ++i) acc[nf][i] = 0.f;

#pragma unroll
  for (int k0 = 0; k0 < 16; ++k0) {
    const bf16x8 af = *reinterpret_cast<const bf16x8*>(abase + (size_t)k0 * 512);
    bf16x8 bfr[4];
#pragma unroll
    for (int nf = 0; nf < 4; ++nf)
      bfr[nf] = *reinterpret_cast<const bf16x8*>(bb + (size_t)(nf * 16 + k0) * 512);
#pragma unroll
    for (int nf = 0; nf < 4; ++nf)
      acc[nf] = __builtin_amdgcn_mfma_f32_32x32x16_bf16(af, bfr[nf], acc[nf], 0, 0, 0);
  }

  const size_t row0 = (size_t)blk * 32;
#pragma unroll
  for (int nf = 0; nf < 4; ++nf) {
    const int col = wv * 128 + nf * 32 + la;
    const float bias = lin_b[col];
#pragma unroll
    for (int reg = 0; reg < 16; ++reg) {
      const int rr = (reg & 3) + 8 * (reg >> 2) + 4 * lb;
      out[(row0 + rr) * NDIM + col] = acc[nf][reg] + bias;
    }
  }
}

extern "C" void kernel_launch(void* const* d_in, const int* in_sizes, int n_in,
                              void* d_out, int out_size, void* d_ws, size_t ws_size,
                              hipStream_t stream) {
  const float* images = (const float*)d_in[0];
  const float* conv_w = (const float*)d_in[1];
  const float* conv_b = (const float*)d_in[2];
  const float* lin_w  = (const float*)d_in[3];
  const float* lin_b  = (const float*)d_in[4];
  float* out = (float*)d_out;
  ushort* wt2 = (ushort*)d_ws;      // 256 KB

  hipLaunchKernelGGL(prep_wt2_kernel, dim3(64), dim3(256), 0, stream, lin_w, wt2);

  if (ws_size >= (size_t)WT_BYTES + FEATS_BYTES + FLAGS_BYTES) {
    ushort* feats2 = (ushort*)((char*)d_ws + WT_BYTES);
    unsigned int* flags = (unsigned int*)((char*)d_ws + WT_BYTES + FEATS_BYTES);
    hipLaunchKernelGGL(pc_kernel, dim3(4096), dim3(256), 0, stream,
                       images, conv_w, conv_b, wt2, lin_b, out, feats2, flags);
  } else {
    hipLaunchKernelGGL(fused_kernel, dim3(NMTILES), dim3(256), 0, stream,
                       images, conv_w, conv_b, wt2, lin_b, out);
  }
}

// Round 12
// 59.710 us; speedup vs baseline: 8.6070x; 8.6070x over previous
//
#include <hip/hip_runtime.h>
#include <hip/hip_bf16.h>
#include <stdint.h>

#define HEIGHT 32
#define WIDTH  8192
#define KDIM   256
#define NDIM   512
#define NSLICES 65536                 // B * S = 64 * 1024
#define NMTILES 2048                  // 32 slices per mtile

typedef float f32x4  __attribute__((ext_vector_type(4)));
typedef float f32x16 __attribute__((ext_vector_type(16)));
typedef short bf16x8 __attribute__((ext_vector_type(8)));

__device__ __forceinline__ ushort f2bf(float x) {
  union { float f; uint32_t u; } un; un.f = x;
  uint32_t u = un.u;
  u += 0x7FFFu + ((u >> 16) & 1u);   // round-to-nearest-even
  return (ushort)(u >> 16);
}

__device__ __forceinline__ void load_row8(float* r, const float* p) {
  f32x4 lo = *reinterpret_cast<const f32x4*>(p);
  f32x4 hi = *reinterpret_cast<const f32x4*>(p + 4);
#pragma unroll
  for (int w = 0; w < 4; ++w) { r[w] = lo[w]; r[4 + w] = hi[w]; }
}

// ---- wt2: B-fragment-tiled layout (proven R7-R10) ----
// wt2[((nb*16 + k0)*64 + lane)*8 + e] = bf16(lin_w[k][n]),
//   n = nb*32 + (lane&31), k = k0*16 + (lane>>5)*8 + e.
__global__ __launch_bounds__(256) void prep_wt2_kernel(const float* __restrict__ lin_w,
                                                       ushort* __restrict__ wt2) {
  const int idx = blockIdx.x * 256 + threadIdx.x;   // 0..16383
  const int ln  = idx & 63;
  const int k0  = (idx >> 6) & 15;
  const int nb  = idx >> 10;
  const int n   = nb * 32 + (ln & 31);
  const int kb  = k0 * 16 + (ln >> 5) * 8;
  bf16x8 p;
#pragma unroll
  for (int e = 0; e < 8; ++e) p[e] = (short)f2bf(lin_w[(size_t)(kb + e) * NDIM + n]);
  *reinterpret_cast<bf16x8*>(wt2 + (size_t)idx * 8) = p;
}

// ---------------- barrier-free fully-fused streaming kernel ----------------
// Wave = (mtile, 128 output cols). Lane ln: slice mtile*32+(ln&31), parity hi=ln>>5.
// Rolling conv window produces the lane's A-frag per k0 (rows h=2*k0+hi), fed
// straight into MFMA against 4 coalesced B-frags. No LDS, no __syncthreads:
// waves drift freely so reads / VALU / MFMA / writes mix chip-wide.
__global__ __launch_bounds__(256) void fused_stream_kernel(
    const float* __restrict__ images, const float* __restrict__ conv_w,
    const float* __restrict__ conv_b, const ushort* __restrict__ wt2,
    const float* __restrict__ lin_b, float* __restrict__ out) {
  const int tid   = threadIdx.x;
  const int lane  = tid & 63;
  const int wv    = tid >> 6;          // 0..3: n-quarter
  const int mtile = blockIdx.x;        // 0..2047
  const int sl    = lane & 31;
  const int hi    = lane >> 5;         // row parity

  float cw[9];
#pragma unroll
  for (int i = 0; i < 9; ++i) cw[i] = conv_w[i];
  const float cb = conv_b[0];

  const int s   = mtile * 32 + sl;     // global slice
  const int b   = s >> 10;             // batch (1024 slices per batch)
  const int slb = s & 1023;
  const float* base = images + (size_t)b * (HEIGHT * WIDTH) + (size_t)slb * 8;

  // rolling window: wa/wb/wc = input rows (2k0+hi-1, 2k0+hi, 2k0+hi+1)
  float wa[8], wb[8], wc[8];
  if (hi) load_row8(wa, base);                       // row 0
  else {
#pragma unroll
    for (int w = 0; w < 8; ++w) wa[w] = 0.f;         // row -1
  }
  load_row8(wb, base + (size_t)hi * WIDTH);          // row hi
  load_row8(wc, base + (size_t)(hi + 1) * WIDTH);    // row hi+1

  const ushort* bbase = wt2 + ((size_t)(wv * 4) * 16) * 512 + (size_t)lane * 8;

  f32x16 acc[4];
#pragma unroll
  for (int nf = 0; nf < 4; ++nf)
#pragma unroll
    for (int i = 0; i < 16; ++i) acc[nf][i] = 0.f;

#pragma unroll
  for (int k0 = 0; k0 < 16; ++k0) {
    // conv output row h = 2*k0 + hi from wa/wb/wc
    float y[8];
#pragma unroll
    for (int w = 0; w < 8; ++w) y[w] = cb;
#pragma unroll
    for (int dw = 0; dw < 3; ++dw) {
      const float c0 = cw[dw], c1 = cw[3 + dw], c2 = cw[6 + dw];
#pragma unroll
      for (int w = 0; w < 8; ++w) {
        const int iw = w + dw - 1;                   // per-slice zero padding in w
        if (iw >= 0 && iw < 8) {
          y[w] = fmaf(wa[iw], c0, y[w]);
          y[w] = fmaf(wb[iw], c1, y[w]);
          y[w] = fmaf(wc[iw], c2, y[w]);
        }
      }
    }
    bf16x8 af;
#pragma unroll
    for (int w = 0; w < 8; ++w) af[w] = (short)f2bf(fmaxf(y[w], 0.f));

    // B-frags: 1 KB contiguous each, L2-resident
    bf16x8 bf0 = *reinterpret_cast<const bf16x8*>(bbase + (size_t)k0 * 512);
    bf16x8 bf1 = *reinterpret_cast<const bf16x8*>(bbase + (size_t)(16 + k0) * 512);
    bf16x8 bf2 = *reinterpret_cast<const bf16x8*>(bbase + (size_t)(32 + k0) * 512);
    bf16x8 bf3 = *reinterpret_cast<const bf16x8*>(bbase + (size_t)(48 + k0) * 512);
    acc[0] = __builtin_amdgcn_mfma_f32_32x32x16_bf16(af, bf0, acc[0], 0, 0, 0);
    acc[1] = __builtin_amdgcn_mfma_f32_32x32x16_bf16(af, bf1, acc[1], 0, 0, 0);
    acc[2] = __builtin_amdgcn_mfma_f32_32x32x16_bf16(af, bf2, acc[2], 0, 0, 0);
    acc[3] = __builtin_amdgcn_mfma_f32_32x32x16_bf16(af, bf3, acc[3], 0, 0, 0);

    // slide window by 2 rows
    if (k0 < 15) {
#pragma unroll
      for (int w = 0; w < 8; ++w) wa[w] = wc[w];
      const int rb_ = 2 * k0 + 2 + hi;               // <= 31 always
      const int rc_ = 2 * k0 + 3 + hi;               // == 32 only at k0=14,hi=1
      load_row8(wb, base + (size_t)rb_ * WIDTH);
      if (rc_ < HEIGHT) load_row8(wc, base + (size_t)rc_ * WIDTH);
      else {
#pragma unroll
        for (int w = 0; w < 8; ++w) wc[w] = 0.f;
      }
    }
  }

  // ---------- epilogue: + bias, fp32 stores ----------
  const size_t row0 = (size_t)mtile * 32;
#pragma unroll
  for (int nf = 0; nf < 4; ++nf) {
    const int col = wv * 128 + nf * 32 + sl;
    const float bias = lin_b[col];
#pragma unroll
    for (int reg = 0; reg < 16; ++reg) {
      const int rr = (reg & 3) + 8 * (reg >> 2) + 4 * hi;
      out[(row0 + rr) * NDIM + col] = acc[nf][reg] + bias;
    }
  }
}

extern "C" void kernel_launch(void* const* d_in, const int* in_sizes, int n_in,
                              void* d_out, int out_size, void* d_ws, size_t ws_size,
                              hipStream_t stream) {
  const float* images = (const float*)d_in[0];
  const float* conv_w = (const float*)d_in[1];
  const float* conv_b = (const float*)d_in[2];
  const float* lin_w  = (const float*)d_in[3];
  const float* lin_b  = (const float*)d_in[4];
  float* out = (float*)d_out;
  ushort* wt2 = (ushort*)d_ws;      // 256 KB

  hipLaunchKernelGGL(prep_wt2_kernel, dim3(64), dim3(256), 0, stream, lin_w, wt2);
  hipLaunchKernelGGL(fused_stream_kernel, dim3(NMTILES), dim3(256), 0, stream,
                     images, conv_w, conv_b, wt2, lin_b, out);
}

// Round 13
// 55.612 us; speedup vs baseline: 9.2412x; 1.0737x over previous
//
#include <hip/hip_runtime.h>
#include <hip/hip_bf16.h>
#include <stdint.h>

#define HEIGHT 32
#define WIDTH  8192
#define KDIM   256
#define NDIM   512
#define NSLICES 65536                 // B * S = 64 * 1024
#define NMTILES 2048                  // 32 slices per mtile

typedef float f32x4  __attribute__((ext_vector_type(4)));
typedef float f32x16 __attribute__((ext_vector_type(16)));
typedef short bf16x8 __attribute__((ext_vector_type(8)));

__device__ __forceinline__ ushort f2bf(float x) {
  union { float f; uint32_t u; } un; un.f = x;
  uint32_t u = un.u;
  u += 0x7FFFu + ((u >> 16) & 1u);   // round-to-nearest-even
  return (ushort)(u >> 16);
}

__device__ __forceinline__ void load_row8(float* r, const float* p) {
  f32x4 lo = *reinterpret_cast<const f32x4*>(p);
  f32x4 hi = *reinterpret_cast<const f32x4*>(p + 4);
#pragma unroll
  for (int w = 0; w < 4; ++w) { r[w] = lo[w]; r[4 + w] = hi[w]; }
}

// ---- wt2: B-fragment-tiled layout (proven R7-R12) ----
// wt2[((nb*16 + k0)*64 + lane)*8 + e] = bf16(lin_w[k][n]),
//   n = nb*32 + (lane&31), k = k0*16 + (lane>>5)*8 + e.
__global__ __launch_bounds__(256) void prep_wt2_kernel(const float* __restrict__ lin_w,
                                                       ushort* __restrict__ wt2) {
  const int idx = blockIdx.x * 256 + threadIdx.x;   // 0..16383
  const int ln  = idx & 63;
  const int k0  = (idx >> 6) & 15;
  const int nb  = idx >> 10;
  const int n   = nb * 32 + (ln & 31);
  const int kb  = k0 * 16 + (ln >> 5) * 8;
  bf16x8 p;
#pragma unroll
  for (int e = 0; e < 8; ++e) p[e] = (short)f2bf(lin_w[(size_t)(kb + e) * NDIM + n]);
  *reinterpret_cast<bf16x8*>(wt2 + (size_t)idx * 8) = p;
}

// ---------------- fused: conv -> LDS A-frags -> MFMA -> out (register-lean) ----------------
// Block = 1 mtile (32 slices), 256 threads. Conv: thread = (slice, 4-row group),
// rolling 3-row window (24 live f32). GEMM: 4 waves x 2 passes of 2 n-frags
// (32 live AGPR). Target <=~110 unified regs -> 4 waves/SIMD.
__global__ __launch_bounds__(256) void fused_kernel(
    const float* __restrict__ images, const float* __restrict__ conv_w,
    const float* __restrict__ conv_b, const ushort* __restrict__ wt2,
    const float* __restrict__ lin_b, float* __restrict__ out) {
  __shared__ ushort A[16 * 64 * 8];   // 16 KB, A-fragment order

  const int tid = threadIdx.x;
  const int blk = blockIdx.x;         // mtile

  float cw[9];
#pragma unroll
  for (int i = 0; i < 9; ++i) cw[i] = conv_w[i];
  const float cb = conv_b[0];

  // ---------- phase 1: conv 32 slices x 32 rows -> A-frags in LDS ----------
  {
    const int sl = tid & 31;          // slice within mtile
    const int q  = tid >> 5;          // 0..7: rows q*4 .. q*4+3
    const int s  = blk * 32 + sl;     // global slice
    const int b  = s >> 10;           // batch (1024 slices per batch)
    const int slb = s & 1023;
    const float* base = images + (size_t)b * (HEIGHT * WIDTH) + (size_t)slb * 8;
    const int h0 = q * 4;

    float pr[8], cu[8], nx[8];
    if (h0 > 0) load_row8(pr, base + (size_t)(h0 - 1) * WIDTH);
    else {
#pragma unroll
      for (int w = 0; w < 8; ++w) pr[w] = 0.f;
    }
    load_row8(cu, base + (size_t)h0 * WIDTH);

#pragma unroll
    for (int i = 0; i < 4; ++i) {
      const int h = h0 + i;
      if (h + 1 < HEIGHT) load_row8(nx, base + (size_t)(h + 1) * WIDTH);
      else {
#pragma unroll
        for (int w = 0; w < 8; ++w) nx[w] = 0.f;
      }
      float y[8];
#pragma unroll
      for (int w = 0; w < 8; ++w) y[w] = cb;
#pragma unroll
      for (int dw = 0; dw < 3; ++dw) {
        const float c0 = cw[dw], c1 = cw[3 + dw], c2 = cw[6 + dw];
#pragma unroll
        for (int w = 0; w < 8; ++w) {
          const int iw = w + dw - 1;            // per-slice zero padding in w
          if (iw >= 0 && iw < 8) {
            y[w] = fmaf(pr[iw], c0, y[w]);
            y[w] = fmaf(cu[iw], c1, y[w]);
            y[w] = fmaf(nx[iw], c2, y[w]);
          }
        }
      }
      bf16x8 pack;
#pragma unroll
      for (int w = 0; w < 8; ++w) pack[w] = (short)f2bf(fmaxf(y[w], 0.f));
      const int ln = ((h & 1) << 5) | sl;
      const int k0 = h >> 1;
      *reinterpret_cast<bf16x8*>(A + ((size_t)k0 * 64 + ln) * 8) = pack;
      // slide window
#pragma unroll
      for (int w = 0; w < 8; ++w) { pr[w] = cu[w]; cu[w] = nx[w]; }
    }
  }
  __syncthreads();

  // ---------- phase 2: [32 x 256] @ [256 x 512]; 4 waves x 2 passes x acc[2] ----------
  const int lane = tid & 63;
  const int wv   = tid >> 6;
  const int la   = lane & 31;
  const int lb   = lane >> 5;
  const size_t row0 = (size_t)blk * 32;

  const ushort* abase = A + (size_t)lane * 8;

#pragma unroll
  for (int pass = 0; pass < 2; ++pass) {
    const int nfb = wv * 4 + pass * 2;          // first of 2 n-frags
    const ushort* bb = wt2 + ((size_t)nfb * 16) * 512 + (size_t)lane * 8;

    f32x16 acc0, acc1;
#pragma unroll
    for (int i = 0; i < 16; ++i) { acc0[i] = 0.f; acc1[i] = 0.f; }

#pragma unroll
    for (int k0 = 0; k0 < 16; ++k0) {
      const bf16x8 af  = *reinterpret_cast<const bf16x8*>(abase + (size_t)k0 * 512);
      const bf16x8 bf0 = *reinterpret_cast<const bf16x8*>(bb + (size_t)k0 * 512);
      const bf16x8 bf1 = *reinterpret_cast<const bf16x8*>(bb + (size_t)(16 + k0) * 512);
      acc0 = __builtin_amdgcn_mfma_f32_32x32x16_bf16(af, bf0, acc0, 0, 0, 0);
      acc1 = __builtin_amdgcn_mfma_f32_32x32x16_bf16(af, bf1, acc1, 0, 0, 0);
    }

    // stores for this pass (keeps write stream spread across the kernel)
#pragma unroll
    for (int nf = 0; nf < 2; ++nf) {
      const int col = (nfb + nf) * 32 + la;
      const float bias = lin_b[col];
      const f32x16& a = nf ? acc1 : acc0;
#pragma unroll
      for (int reg = 0; reg < 16; ++reg) {
        const int rr = (reg & 3) + 8 * (reg >> 2) + 4 * lb;
        out[(row0 + rr) * NDIM + col] = a[reg] + bias;
      }
    }
  }
}

extern "C" void kernel_launch(void* const* d_in, const int* in_sizes, int n_in,
                              void* d_out, int out_size, void* d_ws, size_t ws_size,
                              hipStream_t stream) {
  const float* images = (const float*)d_in[0];
  const float* conv_w = (const float*)d_in[1];
  const float* conv_b = (const float*)d_in[2];
  const float* lin_w  = (const float*)d_in[3];
  const float* lin_b  = (const float*)d_in[4];
  float* out = (float*)d_out;
  ushort* wt2 = (ushort*)d_ws;      // 256 KB

  hipLaunchKernelGGL(prep_wt2_kernel, dim3(64), dim3(256), 0, stream, lin_w, wt2);
  hipLaunchKernelGGL(fused_kernel, dim3(NMTILES), dim3(256), 0, stream,
                     images, conv_w, conv_b, wt2, lin_b, out);
}